// Round 2
// baseline (241.082 us; speedup 1.0000x reference)
//
#include <hip/hip_runtime.h>

#define TOPK 10
#define EPSF 1e-9f

// ---------------------------------------------------------------------------
// K1: one block per (b,j) gt row.
//  - compute IoU(gt_j, pd_a) for all a -> overlaps[row*A+a]   (stored, f32)
//  - metrics[a] = in_gts ? sqrt(score)*iou^6 : 0  in LDS
//  - exact top-10 (value desc, tie -> lowest index) via iterated argmax
//    (matches jax.lax.top_k incl. zero-metric fill at lowest indices)
//  - mask_pos[row*A+a] = (a in top10 && valid && in_gts) ? 1 : 0
// ---------------------------------------------------------------------------
__global__ __launch_bounds__(256) void k_row(
    const float* __restrict__ pd_scores, const float* __restrict__ pd_bboxes,
    const float* __restrict__ anc, const int* __restrict__ gt_labels,
    const float* __restrict__ gt_bboxes,
    float* __restrict__ overlaps, unsigned char* __restrict__ maskp,
    int A, int n, int C)
{
    extern __shared__ float smet[];     // A floats
    __shared__ float rv[256];
    __shared__ int   ri[256];

    const int row = blockIdx.x;          // b*n + j
    const int b   = row / n;
    const int tid = threadIdx.x;

    const float4 g = *(const float4*)(gt_bboxes + (size_t)row * 4);
    const int    c = gt_labels[row];
    const float* ps = pd_scores + ((size_t)b * A) * C + c;
    const float4* pb = (const float4*)(pd_bboxes + (size_t)b * A * 4);
    const float2* an2 = (const float2*)anc;
    const size_t rowbase = (size_t)row * A;
    const float ga = fmaxf(g.z - g.x, 0.f) * fmaxf(g.w - g.y, 0.f);

    for (int a = tid; a < A; a += 256) {
        float4 p = pb[a];
        // IoU with exact reference op order
        float ow = fmaxf(fminf(g.z, p.z) - fmaxf(g.x, p.x), 0.f) *
                   fmaxf(fminf(g.w, p.w) - fmaxf(g.y, p.y), 0.f);
        float pa = fmaxf(p.z - p.x, 0.f) * fmaxf(p.w - p.y, 0.f);
        float iou = ow / (ga + pa - ow + EPSF);
        overlaps[rowbase + a] = iou;
        maskp[rowbase + a] = 0;

        float2 ap = an2[a];
        float dmin = fminf(fminf(ap.x - g.x, ap.y - g.y),
                           fminf(g.z - ap.x, g.w - ap.y));
        float met = 0.f;
        if (dmin > EPSF) {                       // ~1% of pairs: gather is cheap
            float s = ps[(size_t)a * C];
            met = sqrtf(s) * powf(iou, 6.0f);
        }
        smet[a] = met;
    }
    __syncthreads();

    // iterated argmax == stable descending top-k (tie -> lowest index)
    for (int t = 0; t < TOPK; ++t) {
        float bv = -1.f; int bi = 0;
        for (int a = tid; a < A; a += 256) {     // ascending a: lowest idx on tie
            float v = smet[a];
            if (v > bv) { bv = v; bi = a; }
        }
        rv[tid] = bv; ri[tid] = bi;
        __syncthreads();
        for (int s = 128; s > 0; s >>= 1) {
            if (tid < s) {
                float v2 = rv[tid + s]; int i2 = ri[tid + s];
                if (v2 > rv[tid] || (v2 == rv[tid] && i2 < ri[tid])) {
                    rv[tid] = v2; ri[tid] = i2;
                }
            }
            __syncthreads();
        }
        float vmax = rv[0]; int imax = ri[0];
        if (t == 0 && !(vmax > EPSF)) break;     // invalid row: no positives
        if (tid == 0) {
            float2 ap = an2[imax];
            float dmin = fminf(fminf(ap.x - g.x, ap.y - g.y),
                               fminf(g.z - ap.x, g.w - ap.y));
            maskp[rowbase + imax] = (dmin > EPSF) ? 1 : 0;
            smet[imax] = -2.f;                   // exclude from next pick
        }
        __syncthreads();
    }
}

// ---------------------------------------------------------------------------
// K2: one thread per (b,a) anchor column.
//  - count assignments; if >1 -> reassign to argmax_j overlaps (over ALL j)
//  - write target labels / bboxes / fg (labels & bboxes unmasked, per ref)
// ---------------------------------------------------------------------------
__global__ __launch_bounds__(256) void k_col(
    const int* __restrict__ gt_labels, const float* __restrict__ gt_bboxes,
    const float* __restrict__ overlaps, unsigned char* __restrict__ maskp,
    float* __restrict__ out_labels, float* __restrict__ out_bboxes,
    float* __restrict__ out_fg, int A, int n, int bs)
{
    int idx = blockIdx.x * 256 + threadIdx.x;
    if (idx >= bs * A) return;
    int b = idx / A;
    int a = idx - b * A;
    size_t base = (size_t)b * n * A + a;

    int cnt = 0, firstj = -1;
    for (int j = 0; j < n; ++j) {
        if (maskp[base + (size_t)j * A]) { cnt++; if (firstj < 0) firstj = j; }
    }
    if (cnt > 1) {
        float bv = overlaps[base]; int bj = 0;   // argmax over all j, tie->lowest
        for (int j = 1; j < n; ++j) {
            float v = overlaps[base + (size_t)j * A];
            if (v > bv) { bv = v; bj = j; }
        }
        for (int j = 0; j < n; ++j)
            maskp[base + (size_t)j * A] = (j == bj) ? 1 : 0;
        firstj = bj; cnt = 1;
    }
    int jt = (firstj < 0) ? 0 : firstj;
    int lab = gt_labels[b * n + jt];
    if (lab < 0) lab = 0;
    out_labels[idx] = (float)lab;
    float4 gb = *(const float4*)(gt_bboxes + (size_t)(b * n + jt) * 4);
    *(float4*)(out_bboxes + (size_t)idx * 4) = gb;
    out_fg[idx] = (cnt > 0) ? 1.f : 0.f;
}

// ---------------------------------------------------------------------------
// K3: one block per (b,j): pos_align = max_a(align*mask), pos_over = max_a(iou*mask)
// align recomputed from stored iou (RAW align metric, not in_gts-masked)
// ---------------------------------------------------------------------------
__global__ __launch_bounds__(256) void k_rowmax(
    const float* __restrict__ pd_scores, const int* __restrict__ gt_labels,
    const float* __restrict__ overlaps, const unsigned char* __restrict__ maskp,
    float* __restrict__ pos_align, float* __restrict__ pos_over,
    int A, int n, int C)
{
    __shared__ float sa[256], sb[256];
    const int row = blockIdx.x;
    const int b   = row / n;
    const int tid = threadIdx.x;
    const int c   = gt_labels[row];
    const float* ps = pd_scores + ((size_t)b * A) * C + c;
    const size_t base = (size_t)row * A;

    float ma = 0.f, mo = 0.f;
    for (int a = tid; a < A; a += 256) {
        if (maskp[base + a]) {
            float iou = overlaps[base + a];
            float al = sqrtf(ps[(size_t)a * C]) * powf(iou, 6.0f);
            ma = fmaxf(ma, al);
            mo = fmaxf(mo, iou);
        }
    }
    sa[tid] = ma; sb[tid] = mo;
    __syncthreads();
    for (int s = 128; s > 0; s >>= 1) {
        if (tid < s) {
            sa[tid] = fmaxf(sa[tid], sa[tid + s]);
            sb[tid] = fmaxf(sb[tid], sb[tid + s]);
        }
        __syncthreads();
    }
    if (tid == 0) { pos_align[row] = sa[0]; pos_over[row] = sb[0]; }
}

// ---------------------------------------------------------------------------
// K4: one thread per (b,a): norm = max_j mask*align*pos_over[j]/(pos_align[j]+eps)
// ---------------------------------------------------------------------------
__global__ __launch_bounds__(256) void k_norm(
    const float* __restrict__ pd_scores, const int* __restrict__ gt_labels,
    const float* __restrict__ overlaps, const unsigned char* __restrict__ maskp,
    const float* __restrict__ pos_align, const float* __restrict__ pos_over,
    float* __restrict__ normv, int A, int n, int C, int bs)
{
    int idx = blockIdx.x * 256 + threadIdx.x;
    if (idx >= bs * A) return;
    int b = idx / A;
    int a = idx - b * A;
    size_t base = (size_t)b * n * A + a;

    float nm = 0.f;
    for (int j = 0; j < n; ++j) {
        if (maskp[base + (size_t)j * A]) {
            float iou = overlaps[base + (size_t)j * A];
            float s = pd_scores[((size_t)b * A + a) * C + gt_labels[b * n + j]];
            float al = sqrtf(s) * powf(iou, 6.0f);
            int row = b * n + j;
            nm = fmaxf(nm, al * pos_over[row] / (pos_align[row] + EPSF));
        }
    }
    normv[idx] = nm;
}

// ---------------------------------------------------------------------------
// K5: one thread per score element (coalesced 43 MB write)
// score[b,a,c] = (fg && c==label) ? norm : 0
// ---------------------------------------------------------------------------
__global__ __launch_bounds__(256) void k_scores(
    const float* __restrict__ out_labels, const float* __restrict__ out_fg,
    const float* __restrict__ normv, float* __restrict__ out_scores,
    int C, int total)
{
    int idx = blockIdx.x * 256 + threadIdx.x;
    if (idx >= total) return;
    int ba = idx / C;
    int c  = idx - ba * C;
    float v = 0.f;
    if (out_fg[ba] > 0.f && (int)out_labels[ba] == c) v = normv[ba];
    out_scores[idx] = v;
}

// ---------------------------------------------------------------------------
extern "C" void kernel_launch(void* const* d_in, const int* in_sizes, int n_in,
                              void* d_out, int out_size, void* d_ws, size_t ws_size,
                              hipStream_t stream)
{
    const float* pd_scores = (const float*)d_in[0];
    const float* pd_bboxes = (const float*)d_in[1];
    const float* anc       = (const float*)d_in[2];
    const int*   gt_labels = (const int*)d_in[3];
    const float* gt_bboxes = (const float*)d_in[4];

    const int C  = 80;                       // NUM_CLASSES
    const int A  = in_sizes[2] / 2;          // 8400
    const int bs = in_sizes[0] / (A * C);    // 16
    const int n  = in_sizes[3] / bs;         // 64
    const int R  = bs * n;                   // 1024 rows
    const int BA = bs * A;                   // 134400 anchor-columns

    // workspace layout (~44 MB)
    size_t off = 0;
    float* overlaps = (float*)((char*)d_ws + off);       off += (size_t)R * A * sizeof(float);
    unsigned char* maskp = (unsigned char*)d_ws + off;   off += (size_t)R * A;
    off = (off + 255) & ~(size_t)255;
    float* pos_align = (float*)((char*)d_ws + off);      off += (size_t)R * sizeof(float);
    float* pos_over  = (float*)((char*)d_ws + off);      off += (size_t)R * sizeof(float);
    off = (off + 255) & ~(size_t)255;
    float* normv = (float*)((char*)d_ws + off);          off += (size_t)BA * sizeof(float);

    // output layout: labels | bboxes | scores | fg  (flat, return order)
    float* out_labels = (float*)d_out;
    float* out_bboxes = out_labels + (size_t)BA;
    float* out_scores = out_bboxes + (size_t)BA * 4;
    float* out_fg     = out_scores + (size_t)BA * C;

    k_row<<<R, 256, (size_t)A * sizeof(float), stream>>>(
        pd_scores, pd_bboxes, anc, gt_labels, gt_bboxes, overlaps, maskp, A, n, C);

    k_col<<<(BA + 255) / 256, 256, 0, stream>>>(
        gt_labels, gt_bboxes, overlaps, maskp,
        out_labels, out_bboxes, out_fg, A, n, bs);

    k_rowmax<<<R, 256, 0, stream>>>(
        pd_scores, gt_labels, overlaps, maskp, pos_align, pos_over, A, n, C);

    k_norm<<<(BA + 255) / 256, 256, 0, stream>>>(
        pd_scores, gt_labels, overlaps, maskp, pos_align, pos_over,
        normv, A, n, C, bs);

    int total = BA * C;
    k_scores<<<(total + 255) / 256, 256, 0, stream>>>(
        out_labels, out_fg, normv, out_scores, C, total);
}

// Round 3
// 173.489 us; speedup vs baseline: 1.3896x; 1.3896x over previous
//
#include <hip/hip_runtime.h>

#define TOPK 10
#define EPSF 1e-9f

typedef unsigned long long u64;

// ---------------------------------------------------------------------------
// K0: zero the [mask64 | pos_align | pos_over] span (ws is poisoned each call)
// ---------------------------------------------------------------------------
__global__ __launch_bounds__(256) void k_init(uint4* __restrict__ p, int n16) {
    int i = blockIdx.x * 256 + threadIdx.x;
    if (i < n16) p[i] = make_uint4(0, 0, 0, 0);
}

// ---------------------------------------------------------------------------
// K1: one block per (b,j) gt row.
//  - IoU(gt_j, pd_a) for all a -> overlaps[row*A+a] (stored once, read later:
//    guarantees bit-identical values everywhere downstream)
//  - metric = in_gts ? sqrt(score)*iou^6 : 0, per-thread register top-10
//    (value desc, index asc on ties == jax.lax.top_k incl. zero-fill)
//  - LDS merge tree (stride 11 to dodge bank conflicts) -> global top-10
//  - for each pick with in_gts: atomicOr bit j into mask64[b*A+a]
// ---------------------------------------------------------------------------
__global__ __launch_bounds__(256) void k_row(
    const float* __restrict__ pd_scores, const float* __restrict__ pd_bboxes,
    const float* __restrict__ anc, const int* __restrict__ gt_labels,
    const float* __restrict__ gt_bboxes,
    float* __restrict__ overlaps, u64* __restrict__ mask64,
    int A, int n, int C)
{
    __shared__ float sv[256 * 11];
    __shared__ int   si[256 * 11];

    const int row = blockIdx.x;          // b*n + j
    const int b   = row / n;
    const int j   = row - b * n;
    const int tid = threadIdx.x;

    const float4 g = *(const float4*)(gt_bboxes + (size_t)row * 4);
    const int    c = gt_labels[row];
    const float* ps = pd_scores + (size_t)b * A * C + c;
    const float4* pb = (const float4*)(pd_bboxes + (size_t)b * A * 4);
    const float2* an2 = (const float2*)anc;
    const size_t rowbase = (size_t)row * A;
    const float ga = fmaxf(g.z - g.x, 0.f) * fmaxf(g.w - g.y, 0.f);

    // per-thread top-10, sorted (v desc, idx asc)
    float tv[TOPK]; int ti[TOPK];
    #pragma unroll
    for (int k = 0; k < TOPK; ++k) { tv[k] = -1.f; ti[k] = 0x7fffffff; }

    for (int a = tid; a < A; a += 256) {
        float4 p = pb[a];
        // IoU with exact reference op order
        float ow = fmaxf(fminf(g.z, p.z) - fmaxf(g.x, p.x), 0.f) *
                   fmaxf(fminf(g.w, p.w) - fmaxf(g.y, p.y), 0.f);
        float pa = fmaxf(p.z - p.x, 0.f) * fmaxf(p.w - p.y, 0.f);
        float iou = ow / (ga + pa - ow + EPSF);
        overlaps[rowbase + a] = iou;

        float2 ap = an2[a];
        float dmin = fminf(fminf(ap.x - g.x, ap.y - g.y),
                           fminf(g.z - ap.x, g.w - ap.y));
        float met = 0.f;
        if (dmin > EPSF) met = sqrtf(ps[(size_t)a * C]) * powf(iou, 6.0f);

        // insert if it beats the current 10th (strict by (v desc, idx asc));
        // ascending a within the thread preserves tie->lowest-index
        if (met > tv[TOPK-1] || (met == tv[TOPK-1] && a < ti[TOPK-1])) {
            tv[TOPK-1] = met; ti[TOPK-1] = a;
            #pragma unroll
            for (int k = TOPK-1; k > 0; --k) {
                if (tv[k] > tv[k-1] || (tv[k] == tv[k-1] && ti[k] < ti[k-1])) {
                    float fv = tv[k]; tv[k] = tv[k-1]; tv[k-1] = fv;
                    int   fi = ti[k]; ti[k] = ti[k-1]; ti[k-1] = fi;
                }
            }
        }
    }

    #pragma unroll
    for (int k = 0; k < TOPK; ++k) { sv[tid*11 + k] = tv[k]; si[tid*11 + k] = ti[k]; }

    // binary merge tree: slot[tid] = top-10 of merge(slot[tid], slot[tid+s])
    for (int s = 128; s > 0; s >>= 1) {
        __syncthreads();
        if (tid < s) {
            const int bA = tid * 11, bB = (tid + s) * 11;
            int pa_ = 0, pb_ = 0;
            float ov[TOPK]; int oi[TOPK];
            #pragma unroll
            for (int k = 0; k < TOPK; ++k) {       // static out idx; LDS runtime in
                float va = sv[bA + pa_], vb = sv[bB + pb_];
                int   ja = si[bA + pa_], jb = si[bB + pb_];
                bool ta = (va > vb) || (va == vb && ja < jb);
                ov[k] = ta ? va : vb; oi[k] = ta ? ja : jb;
                pa_ += ta; pb_ += !ta;
            }
            #pragma unroll
            for (int k = 0; k < TOPK; ++k) { sv[bA + k] = ov[k]; si[bA + k] = oi[k]; }
        }
    }
    __syncthreads();

    // valid row (max metric > EPS): commit the 10 picks where in_gts holds
    if (sv[0] > EPSF && tid < TOPK) {
        int a = si[tid];
        float2 ap = an2[a];
        float dmin = fminf(fminf(ap.x - g.x, ap.y - g.y),
                           fminf(g.z - ap.x, g.w - ap.y));
        if (dmin > EPSF)
            atomicOr(&mask64[(size_t)b * A + a], 1ull << j);
    }
}

// ---------------------------------------------------------------------------
// K2: one thread per (b,a).
//  - popc>1 -> reassign to argmax_j of stored overlaps column (tie->lowest j)
//  - write labels/bboxes/fg; fold pos_align/pos_over row-maxima via atomicMax
//    (float-as-int valid: all values >= 0; fmax assoc/comm -> bit-identical)
// ---------------------------------------------------------------------------
__global__ __launch_bounds__(256) void k_col(
    const float* __restrict__ pd_scores,
    const int* __restrict__ gt_labels, const float* __restrict__ gt_bboxes,
    const float* __restrict__ overlaps, u64* __restrict__ mask64,
    float* __restrict__ out_labels, float* __restrict__ out_bboxes,
    float* __restrict__ out_fg,
    float* __restrict__ pos_align, float* __restrict__ pos_over,
    int A, int n, int C)
{
    __shared__ float4 sg[64];
    __shared__ int    sl[64];
    const int b = blockIdx.y;
    const int a = blockIdx.x * 256 + threadIdx.x;
    if (threadIdx.x < n) {
        sg[threadIdx.x] = ((const float4*)gt_bboxes)[b * n + threadIdx.x];
        sl[threadIdx.x] = gt_labels[b * n + threadIdx.x];
    }
    __syncthreads();
    if (a >= A) return;

    const size_t midx = (size_t)b * A + a;
    u64 m = mask64[midx];
    int pc = __popcll(m);
    int jt = 0;
    if (pc > 1) {
        const float* col = overlaps + (size_t)b * n * A + a;
        float bv = col[0]; int bj = 0;
        for (int jj = 1; jj < n; ++jj) {
            float v = col[(size_t)jj * A];
            if (v > bv) { bv = v; bj = jj; }
        }
        jt = bj; mask64[midx] = 1ull << bj; pc = 1;
    } else if (pc == 1) {
        jt = __ffsll(m) - 1;
    }

    int lab = sl[jt];
    out_labels[midx] = (float)(lab < 0 ? 0 : lab);
    ((float4*)out_bboxes)[midx] = sg[jt];
    out_fg[midx] = pc ? 1.f : 0.f;

    if (pc) {
        int rowj = b * n + jt;
        float iou = overlaps[(size_t)rowj * A + a];
        float s = pd_scores[((size_t)b * A + a) * C + lab];   // raw label gather
        float al = sqrtf(s) * powf(iou, 6.0f);
        atomicMax((int*)&pos_align[rowj], __float_as_int(al));
        atomicMax((int*)&pos_over[rowj],  __float_as_int(iou));
    }
}

// ---------------------------------------------------------------------------
// K3: one thread per (b,a): resolved mask has popc<=1 ->
// norm = align * pos_over[row] / (pos_align[row] + eps)  (0 if background)
// ---------------------------------------------------------------------------
__global__ __launch_bounds__(256) void k_norm(
    const float* __restrict__ pd_scores, const int* __restrict__ gt_labels,
    const float* __restrict__ overlaps, const u64* __restrict__ mask64,
    const float* __restrict__ pos_align, const float* __restrict__ pos_over,
    float* __restrict__ normv, int A, int n, int C, int total)
{
    int idx = blockIdx.x * 256 + threadIdx.x;
    if (idx >= total) return;
    int b = idx / A;
    int a = idx - b * A;
    u64 m = mask64[idx];
    float nm = 0.f;
    if (m) {
        int jj = __ffsll(m) - 1;
        int rowj = b * n + jj;
        float iou = overlaps[(size_t)rowj * A + a];
        float s = pd_scores[(size_t)idx * C + gt_labels[rowj]];
        float al = sqrtf(s) * powf(iou, 6.0f);
        nm = al * pos_over[rowj] / (pos_align[rowj] + EPSF);
    }
    normv[idx] = nm;
}

// ---------------------------------------------------------------------------
// K4: float4 per thread over scores: (fg && c==label) ? norm : 0
// ---------------------------------------------------------------------------
__global__ __launch_bounds__(256) void k_scores(
    const float* __restrict__ out_labels, const float* __restrict__ out_fg,
    const float* __restrict__ normv, float4* __restrict__ out_scores,
    int C4, int quads)
{
    int idx = blockIdx.x * 256 + threadIdx.x;
    if (idx >= quads) return;
    int ba = idx / C4;
    int q  = idx - ba * C4;
    float4 v = make_float4(0.f, 0.f, 0.f, 0.f);
    if (out_fg[ba] > 0.f) {
        int r = (int)out_labels[ba] - q * 4;
        float nv = normv[ba];
        v.x = (r == 0) ? nv : 0.f;
        v.y = (r == 1) ? nv : 0.f;
        v.z = (r == 2) ? nv : 0.f;
        v.w = (r == 3) ? nv : 0.f;
    }
    out_scores[idx] = v;
}

// ---------------------------------------------------------------------------
extern "C" void kernel_launch(void* const* d_in, const int* in_sizes, int n_in,
                              void* d_out, int out_size, void* d_ws, size_t ws_size,
                              hipStream_t stream)
{
    const float* pd_scores = (const float*)d_in[0];
    const float* pd_bboxes = (const float*)d_in[1];
    const float* anc       = (const float*)d_in[2];
    const int*   gt_labels = (const int*)d_in[3];
    const float* gt_bboxes = (const float*)d_in[4];

    const int C  = 80;                       // NUM_CLASSES
    const int A  = in_sizes[2] / 2;          // 8400
    const int bs = in_sizes[0] / (A * C);    // 16
    const int n  = in_sizes[3] / bs;         // 64
    const int R  = bs * n;                   // 1024
    const int BA = bs * A;                   // 134400

    // ws layout: [mask64 BA*8 | pos_align R*4 | pos_over R*4] (zeroed) | overlaps | normv
    size_t off = 0;
    u64*   mask64    = (u64*)((char*)d_ws + off);   off += (size_t)BA * 8;
    float* pos_align = (float*)((char*)d_ws + off); off += (size_t)R * 4;
    float* pos_over  = (float*)((char*)d_ws + off); off += (size_t)R * 4;
    size_t zero_bytes = off;
    float* overlaps  = (float*)((char*)d_ws + off); off += (size_t)R * A * 4;
    float* normv     = (float*)((char*)d_ws + off); off += (size_t)BA * 4;

    float* out_labels = (float*)d_out;
    float* out_bboxes = out_labels + (size_t)BA;
    float* out_scores = out_bboxes + (size_t)BA * 4;
    float* out_fg     = out_scores + (size_t)BA * C;

    int n16 = (int)(zero_bytes / 16);
    k_init<<<(n16 + 255) / 256, 256, 0, stream>>>((uint4*)d_ws, n16);

    k_row<<<R, 256, 0, stream>>>(
        pd_scores, pd_bboxes, anc, gt_labels, gt_bboxes, overlaps, mask64, A, n, C);

    k_col<<<dim3((A + 255) / 256, bs), 256, 0, stream>>>(
        pd_scores, gt_labels, gt_bboxes, overlaps, mask64,
        out_labels, out_bboxes, out_fg, pos_align, pos_over, A, n, C);

    k_norm<<<(BA + 255) / 256, 256, 0, stream>>>(
        pd_scores, gt_labels, overlaps, mask64, pos_align, pos_over,
        normv, A, n, C, BA);

    int quads = BA * (C / 4);
    k_scores<<<(quads + 255) / 256, 256, 0, stream>>>(
        out_labels, out_fg, normv, (float4*)out_scores, C / 4, quads);
}

// Round 4
// 172.542 us; speedup vs baseline: 1.3972x; 1.0055x over previous
//
#include <hip/hip_runtime.h>

#define TOPK 10
#define EPSF 1e-9f
#define CHUNKS 4

typedef unsigned long long u64;
typedef unsigned int u32;

// ---------------------------------------------------------------------------
// K0: zero [mask64 | pos_align | pos_over] (ws is poisoned before every call)
// ---------------------------------------------------------------------------
__global__ __launch_bounds__(256) void k_init(uint4* __restrict__ p, int n16) {
    int i = blockIdx.x * 256 + threadIdx.x;
    if (i < n16) p[i] = make_uint4(0, 0, 0, 0);
}

// ---------------------------------------------------------------------------
// K1: grid (CHUNKS, R). Each block: IoU + metric for its anchor chunk,
// partial top-10 as u64 keys:  key = (met_bits << 32) | (0x7fffffff - a)
// (met >= 0 always -> float bits monotone; complement index -> tie = lowest a)
// This ordering == jax.lax.top_k (value desc, stable) incl. zero-metric fill.
// ---------------------------------------------------------------------------
__global__ __launch_bounds__(256) void k_chunk(
    const float* __restrict__ pd_scores, const float* __restrict__ pd_bboxes,
    const float* __restrict__ anc, const int* __restrict__ gt_labels,
    const float* __restrict__ gt_bboxes,
    float* __restrict__ overlaps, u64* __restrict__ part,
    int A, int n, int C)
{
    __shared__ u64 sk[256 * 11];

    const int row = blockIdx.y;          // b*n + j
    const int b   = row / n;
    const int tid = threadIdx.x;
    const int CS  = (A + CHUNKS - 1) / CHUNKS;
    const int a0  = blockIdx.x * CS;
    const int a1  = min(A, a0 + CS);

    const float4 g = *(const float4*)(gt_bboxes + (size_t)row * 4);
    const int    c = gt_labels[row];
    const float* ps = pd_scores + (size_t)b * A * C + c;
    const float4* pb = (const float4*)(pd_bboxes + (size_t)b * A * 4);
    const float2* an2 = (const float2*)anc;
    const size_t rowbase = (size_t)row * A;
    const float ga = fmaxf(g.z - g.x, 0.f) * fmaxf(g.w - g.y, 0.f);

    u64 tk[TOPK];
    #pragma unroll
    for (int k = 0; k < TOPK; ++k) tk[k] = 0;   // empty: loses to any real key

    for (int a = a0 + tid; a < a1; a += 256) {
        float4 p = pb[a];
        // IoU with exact reference op order
        float ow = fmaxf(fminf(g.z, p.z) - fmaxf(g.x, p.x), 0.f) *
                   fmaxf(fminf(g.w, p.w) - fmaxf(g.y, p.y), 0.f);
        float pa = fmaxf(p.z - p.x, 0.f) * fmaxf(p.w - p.y, 0.f);
        float iou = ow / (ga + pa - ow + EPSF);
        overlaps[rowbase + a] = iou;

        float2 ap = an2[a];
        float dmin = fminf(fminf(ap.x - g.x, ap.y - g.y),
                           fminf(g.z - ap.x, g.w - ap.y));
        float met = 0.f;
        if (dmin > EPSF) met = sqrtf(ps[(size_t)a * C]) * powf(iou, 6.0f);

        u64 key = ((u64)__float_as_uint(met) << 32) | (u32)(0x7fffffff - a);
        if (key > tk[TOPK-1]) {
            tk[TOPK-1] = key;
            #pragma unroll
            for (int k = TOPK-1; k > 0; --k)
                if (tk[k] > tk[k-1]) { u64 t = tk[k]; tk[k] = tk[k-1]; tk[k-1] = t; }
        }
    }

    #pragma unroll
    for (int k = 0; k < TOPK; ++k) sk[tid * 11 + k] = tk[k];

    // binary merge tree: slot[tid] = top-10 of merge(slot[tid], slot[tid+s])
    for (int s = 128; s > 0; s >>= 1) {
        __syncthreads();
        if (tid < s) {
            const int bA = tid * 11, bB = (tid + s) * 11;
            int pa_ = 0, pb_ = 0;
            u64 out[TOPK];
            #pragma unroll
            for (int k = 0; k < TOPK; ++k) {
                u64 va = sk[bA + pa_], vb = sk[bB + pb_];
                bool ta = va > vb;
                out[k] = ta ? va : vb;
                pa_ += ta; pb_ += !ta;
            }
            #pragma unroll
            for (int k = 0; k < TOPK; ++k) sk[bA + k] = out[k];
        }
    }
    __syncthreads();

    if (tid < TOPK)
        part[((size_t)row * CHUNKS + blockIdx.x) * TOPK + tid] = sk[tid];
}

// ---------------------------------------------------------------------------
// K2: one thread per row: 4-way merge of sorted chunk lists -> global top-10;
// validity (max metric > EPS); commit in_gts picks via atomicOr bit j.
// ---------------------------------------------------------------------------
__global__ __launch_bounds__(256) void k_merge(
    const float* __restrict__ anc, const float* __restrict__ gt_bboxes,
    const u64* __restrict__ part, u64* __restrict__ mask64,
    int A, int n, int R)
{
    int row = blockIdx.x * 256 + threadIdx.x;
    if (row >= R) return;
    int b = row / n;
    int j = row - b * n;
    const u64* l = part + (size_t)row * CHUNKS * TOPK;
    const float4 g = *(const float4*)(gt_bboxes + (size_t)row * 4);
    const float2* an2 = (const float2*)anc;

    int p0 = 0, p1 = 0, p2 = 0, p3 = 0;      // named: keep in registers
    for (int k = 0; k < TOPK; ++k) {
        u64 v0 = (p0 < TOPK) ? l[p0]            : 0;
        u64 v1 = (p1 < TOPK) ? l[TOPK + p1]     : 0;
        u64 v2 = (p2 < TOPK) ? l[2 * TOPK + p2] : 0;
        u64 v3 = (p3 < TOPK) ? l[3 * TOPK + p3] : 0;
        u64 bv = v0; int best = 0;
        if (v1 > bv) { bv = v1; best = 1; }
        if (v2 > bv) { bv = v2; best = 2; }
        if (v3 > bv) { bv = v3; best = 3; }
        p0 += (best == 0); p1 += (best == 1);
        p2 += (best == 2); p3 += (best == 3);

        if (k == 0) {
            float m0 = __uint_as_float((u32)(bv >> 32));
            if (!(m0 > EPSF)) break;             // invalid row: no positives
        }
        int a = 0x7fffffff - (int)(u32)(bv & 0xffffffffu);
        float2 ap = an2[a];
        float dmin = fminf(fminf(ap.x - g.x, ap.y - g.y),
                           fminf(g.z - ap.x, g.w - ap.y));
        if (dmin > EPSF)
            atomicOr(&mask64[(size_t)b * A + a], 1ull << j);
    }
}

// ---------------------------------------------------------------------------
// K3: one thread per (b,a).
//  - popc>1 -> reassign to argmax_j of stored overlaps column (tie->lowest j)
//  - write labels/bboxes/fg; fold pos_align/pos_over row maxima via atomicMax
//    (float-as-int valid: all values >= 0; fmax assoc/comm -> bit-identical)
// ---------------------------------------------------------------------------
__global__ __launch_bounds__(256) void k_col(
    const float* __restrict__ pd_scores,
    const int* __restrict__ gt_labels, const float* __restrict__ gt_bboxes,
    const float* __restrict__ overlaps, u64* __restrict__ mask64,
    float* __restrict__ out_labels, float* __restrict__ out_bboxes,
    float* __restrict__ out_fg,
    float* __restrict__ pos_align, float* __restrict__ pos_over,
    int A, int n, int C)
{
    __shared__ float4 sg[64];
    __shared__ int    sl[64];
    const int b = blockIdx.y;
    const int a = blockIdx.x * 256 + threadIdx.x;
    if (threadIdx.x < n) {
        sg[threadIdx.x] = ((const float4*)gt_bboxes)[b * n + threadIdx.x];
        sl[threadIdx.x] = gt_labels[b * n + threadIdx.x];
    }
    __syncthreads();
    if (a >= A) return;

    const size_t midx = (size_t)b * A + a;
    u64 m = mask64[midx];
    int pc = __popcll(m);
    int jt = 0;
    if (pc > 1) {
        const float* col = overlaps + (size_t)b * n * A + a;
        float bv = col[0]; int bj = 0;
        for (int jj = 1; jj < n; ++jj) {
            float v = col[(size_t)jj * A];
            if (v > bv) { bv = v; bj = jj; }
        }
        jt = bj; mask64[midx] = 1ull << bj; pc = 1;
    } else if (pc == 1) {
        jt = __ffsll(m) - 1;
    }

    int lab = sl[jt];
    out_labels[midx] = (float)(lab < 0 ? 0 : lab);
    ((float4*)out_bboxes)[midx] = sg[jt];
    out_fg[midx] = pc ? 1.f : 0.f;

    if (pc) {
        int rowj = b * n + jt;
        float iou = overlaps[(size_t)rowj * A + a];
        float s = pd_scores[((size_t)b * A + a) * C + lab];
        float al = sqrtf(s) * powf(iou, 6.0f);
        atomicMax((int*)&pos_align[rowj], __float_as_int(al));
        atomicMax((int*)&pos_over[rowj],  __float_as_int(iou));
    }
}

// ---------------------------------------------------------------------------
// K4: one thread per (b,a): resolved mask popc<=1 ->
// norm = align * pos_over[row] / (pos_align[row] + eps)
// ---------------------------------------------------------------------------
__global__ __launch_bounds__(256) void k_norm(
    const float* __restrict__ pd_scores, const int* __restrict__ gt_labels,
    const float* __restrict__ overlaps, const u64* __restrict__ mask64,
    const float* __restrict__ pos_align, const float* __restrict__ pos_over,
    float* __restrict__ normv, int A, int n, int C, int total)
{
    int idx = blockIdx.x * 256 + threadIdx.x;
    if (idx >= total) return;
    int b = idx / A;
    int a = idx - b * A;
    u64 m = mask64[idx];
    float nm = 0.f;
    if (m) {
        int jj = __ffsll(m) - 1;
        int rowj = b * n + jj;
        float iou = overlaps[(size_t)rowj * A + a];
        float s = pd_scores[(size_t)idx * C + gt_labels[rowj]];
        float al = sqrtf(s) * powf(iou, 6.0f);
        nm = al * pos_over[rowj] / (pos_align[rowj] + EPSF);
    }
    normv[idx] = nm;
}

// ---------------------------------------------------------------------------
// K5: float4 per thread: score[b,a,c] = (fg && c==label) ? norm : 0
// ---------------------------------------------------------------------------
__global__ __launch_bounds__(256) void k_scores(
    const float* __restrict__ out_labels, const float* __restrict__ out_fg,
    const float* __restrict__ normv, float4* __restrict__ out_scores,
    int C4, int quads)
{
    int idx = blockIdx.x * 256 + threadIdx.x;
    if (idx >= quads) return;
    int ba = idx / C4;
    int q  = idx - ba * C4;
    float4 v = make_float4(0.f, 0.f, 0.f, 0.f);
    if (out_fg[ba] > 0.f) {
        int r = (int)out_labels[ba] - q * 4;
        float nv = normv[ba];
        v.x = (r == 0) ? nv : 0.f;
        v.y = (r == 1) ? nv : 0.f;
        v.z = (r == 2) ? nv : 0.f;
        v.w = (r == 3) ? nv : 0.f;
    }
    out_scores[idx] = v;
}

// ---------------------------------------------------------------------------
extern "C" void kernel_launch(void* const* d_in, const int* in_sizes, int n_in,
                              void* d_out, int out_size, void* d_ws, size_t ws_size,
                              hipStream_t stream)
{
    const float* pd_scores = (const float*)d_in[0];
    const float* pd_bboxes = (const float*)d_in[1];
    const float* anc       = (const float*)d_in[2];
    const int*   gt_labels = (const int*)d_in[3];
    const float* gt_bboxes = (const float*)d_in[4];

    const int C  = 80;                       // NUM_CLASSES
    const int A  = in_sizes[2] / 2;          // 8400
    const int bs = in_sizes[0] / (A * C);    // 16
    const int n  = in_sizes[3] / bs;         // 64
    const int R  = bs * n;                   // 1024
    const int BA = bs * A;                   // 134400

    // ws: [mask64 | pos_align | pos_over] (zeroed) | overlaps | normv | part
    size_t off = 0;
    u64*   mask64    = (u64*)((char*)d_ws + off);   off += (size_t)BA * 8;
    float* pos_align = (float*)((char*)d_ws + off); off += (size_t)R * 4;
    float* pos_over  = (float*)((char*)d_ws + off); off += (size_t)R * 4;
    size_t zero_bytes = off;
    float* overlaps  = (float*)((char*)d_ws + off); off += (size_t)R * A * 4;
    float* normv     = (float*)((char*)d_ws + off); off += (size_t)BA * 4;
    u64*   part      = (u64*)((char*)d_ws + off);   off += (size_t)R * CHUNKS * TOPK * 8;

    float* out_labels = (float*)d_out;
    float* out_bboxes = out_labels + (size_t)BA;
    float* out_scores = out_bboxes + (size_t)BA * 4;
    float* out_fg     = out_scores + (size_t)BA * C;

    int n16 = (int)(zero_bytes / 16);
    k_init<<<(n16 + 255) / 256, 256, 0, stream>>>((uint4*)d_ws, n16);

    k_chunk<<<dim3(CHUNKS, R), 256, 0, stream>>>(
        pd_scores, pd_bboxes, anc, gt_labels, gt_bboxes, overlaps, part, A, n, C);

    k_merge<<<(R + 255) / 256, 256, 0, stream>>>(
        anc, gt_bboxes, part, mask64, A, n, R);

    k_col<<<dim3((A + 255) / 256, bs), 256, 0, stream>>>(
        pd_scores, gt_labels, gt_bboxes, overlaps, mask64,
        out_labels, out_bboxes, out_fg, pos_align, pos_over, A, n, C);

    k_norm<<<(BA + 255) / 256, 256, 0, stream>>>(
        pd_scores, gt_labels, overlaps, mask64, pos_align, pos_over,
        normv, A, n, C, BA);

    int quads = BA * (C / 4);
    k_scores<<<(quads + 255) / 256, 256, 0, stream>>>(
        out_labels, out_fg, normv, (float4*)out_scores, C / 4, quads);
}

// Round 6
// 169.013 us; speedup vs baseline: 1.4264x; 1.0209x over previous
//
#include <hip/hip_runtime.h>

#define TOPK 10
#define EPSF 1e-9f
#define CHUNKS 8

typedef unsigned long long u64;
typedef unsigned int u32;

// ---------------------------------------------------------------------------
// K0: zero [mask64 | pos_align | pos_over] (ws is poisoned before every call)
// ---------------------------------------------------------------------------
__global__ __launch_bounds__(256) void k_init(uint4* __restrict__ p, int n16) {
    int i = blockIdx.x * 256 + threadIdx.x;
    if (i < n16) p[i] = make_uint4(0, 0, 0, 0);
}

// ---------------------------------------------------------------------------
// K1: ONE WAVE per (row, chunk). 8192 waves, no LDS, no syncthreads.
//  - scan: IoU -> overlaps store; metric key = (met_bits<<32)|(0x7fffffff-a)
//    (order-isomorphic to jax.lax.top_k: value desc, index asc, incl. zeros)
//  - per-lane sorted top-10 in registers (static-index insertion)
//  - 10 rounds of wave-argmax (shfl_xor butterfly) + owner pop -> chunk top-10
// ---------------------------------------------------------------------------
__global__ __launch_bounds__(256) void k_chunk(
    const float* __restrict__ pd_scores, const float* __restrict__ pd_bboxes,
    const float* __restrict__ anc, const int* __restrict__ gt_labels,
    const float* __restrict__ gt_bboxes,
    float* __restrict__ overlaps, u64* __restrict__ part,
    int A, int n, int C)
{
    const int gw   = blockIdx.x * 4 + (threadIdx.x >> 6);   // global wave id
    const int lane = threadIdx.x & 63;
    const int row  = gw >> 3;                               // CHUNKS = 8
    const int ch   = gw & (CHUNKS - 1);
    const int b    = row / n;
    const int CS   = (A + CHUNKS - 1) / CHUNKS;             // 1050
    const int a0   = ch * CS;
    const int a1   = min(A, a0 + CS);

    const float4 g = *(const float4*)(gt_bboxes + (size_t)row * 4);
    const int    c = gt_labels[row];
    const float* ps = pd_scores + (size_t)b * A * C + c;
    const float4* pb = (const float4*)(pd_bboxes + (size_t)b * A * 4);
    const float2* an2 = (const float2*)anc;
    const size_t rowbase = (size_t)row * A;
    const float ga = fmaxf(g.z - g.x, 0.f) * fmaxf(g.w - g.y, 0.f);

    u64 tk[TOPK];
    #pragma unroll
    for (int k = 0; k < TOPK; ++k) tk[k] = 0;   // empty slot: loses to any key

    for (int a = a0 + lane; a < a1; a += 64) {
        float4 p = pb[a];
        // IoU with exact reference op order
        float ow = fmaxf(fminf(g.z, p.z) - fmaxf(g.x, p.x), 0.f) *
                   fmaxf(fminf(g.w, p.w) - fmaxf(g.y, p.y), 0.f);
        float pa = fmaxf(p.z - p.x, 0.f) * fmaxf(p.w - p.y, 0.f);
        float iou = ow / (ga + pa - ow + EPSF);
        overlaps[rowbase + a] = iou;

        float2 ap = an2[a];
        float dmin = fminf(fminf(ap.x - g.x, ap.y - g.y),
                           fminf(g.z - ap.x, g.w - ap.y));
        float met = 0.f;
        if (dmin > EPSF) met = sqrtf(ps[(size_t)a * C]) * powf(iou, 6.0f);

        u64 key = ((u64)__float_as_uint(met) << 32) | (u32)(0x7fffffff - a);
        // after the first 10 inserts, zero-met keys descend -> no more inserts
        if (key > tk[TOPK-1]) {
            tk[TOPK-1] = key;
            #pragma unroll
            for (int k = TOPK-1; k > 0; --k)
                if (tk[k] > tk[k-1]) { u64 t = tk[k]; tk[k] = tk[k-1]; tk[k-1] = t; }
        }
    }

    // 10 rounds: wave-max of list heads; unique owner pops (keys are unique)
    u64 mine = 0;
    #pragma unroll
    for (int r = 0; r < TOPK; ++r) {
        u64 m = tk[0];
        #pragma unroll
        for (int s = 1; s < 64; s <<= 1) {
            u64 o = __shfl_xor(m, s, 64);
            m = (o > m) ? o : m;
        }
        if (lane == r) mine = m;
        if (tk[0] == m) {                        // exactly one lane owns m
            #pragma unroll
            for (int k = 0; k < TOPK - 1; ++k) tk[k] = tk[k + 1];
            tk[TOPK-1] = 0;
        }
    }
    if (lane < TOPK)
        part[((size_t)row * CHUNKS + ch) * TOPK + lane] = mine;
}

// ---------------------------------------------------------------------------
// K2: one thread per row: 8-way merge of sorted chunk lists -> global top-10;
// validity (max metric > EPS); commit in_gts picks via atomicOr bit j.
// ---------------------------------------------------------------------------
__global__ __launch_bounds__(64) void k_merge(
    const float* __restrict__ anc, const float* __restrict__ gt_bboxes,
    const u64* __restrict__ part, u64* __restrict__ mask64,
    int A, int n, int R)
{
    int row = blockIdx.x * 64 + threadIdx.x;
    if (row >= R) return;
    int b = row / n;
    int j = row - b * n;
    const u64* l = part + (size_t)row * CHUNKS * TOPK;
    const float4 g = *(const float4*)(gt_bboxes + (size_t)row * 4);
    const float2* an2 = (const float2*)anc;

    int p0 = 0, p1 = 0, p2 = 0, p3 = 0, p4 = 0, p5 = 0, p6 = 0, p7 = 0;
    for (int k = 0; k < TOPK; ++k) {
        u64 v0 = (p0 < TOPK) ? l[0*TOPK + p0] : 0;
        u64 v1 = (p1 < TOPK) ? l[1*TOPK + p1] : 0;
        u64 v2 = (p2 < TOPK) ? l[2*TOPK + p2] : 0;
        u64 v3 = (p3 < TOPK) ? l[3*TOPK + p3] : 0;
        u64 v4 = (p4 < TOPK) ? l[4*TOPK + p4] : 0;
        u64 v5 = (p5 < TOPK) ? l[5*TOPK + p5] : 0;
        u64 v6 = (p6 < TOPK) ? l[6*TOPK + p6] : 0;
        u64 v7 = (p7 < TOPK) ? l[7*TOPK + p7] : 0;
        u64 bv = v0; int best = 0;
        if (v1 > bv) { bv = v1; best = 1; }
        if (v2 > bv) { bv = v2; best = 2; }
        if (v3 > bv) { bv = v3; best = 3; }
        if (v4 > bv) { bv = v4; best = 4; }
        if (v5 > bv) { bv = v5; best = 5; }
        if (v6 > bv) { bv = v6; best = 6; }
        if (v7 > bv) { bv = v7; best = 7; }
        p0 += (best == 0); p1 += (best == 1); p2 += (best == 2); p3 += (best == 3);
        p4 += (best == 4); p5 += (best == 5); p6 += (best == 6); p7 += (best == 7);

        if (k == 0) {
            float m0 = __uint_as_float((u32)(bv >> 32));
            if (!(m0 > EPSF)) break;             // invalid row: no positives
        }
        int a = 0x7fffffff - (int)(u32)(bv & 0xffffffffu);
        float2 ap = an2[a];
        float dmin = fminf(fminf(ap.x - g.x, ap.y - g.y),
                           fminf(g.z - ap.x, g.w - ap.y));
        if (dmin > EPSF)
            atomicOr(&mask64[(size_t)b * A + a], 1ull << j);
    }
}

// ---------------------------------------------------------------------------
// K3: one thread per (b,a).
//  - popc>1 -> reassign to argmax_j of stored overlaps column (tie->lowest j)
//  - write labels/bboxes/fg; fold pos_align/pos_over row maxima via atomicMax
//    (float-as-int valid: all values >= 0; fmax assoc/comm -> bit-identical)
// ---------------------------------------------------------------------------
__global__ __launch_bounds__(256) void k_col(
    const float* __restrict__ pd_scores,
    const int* __restrict__ gt_labels, const float* __restrict__ gt_bboxes,
    const float* __restrict__ overlaps, u64* __restrict__ mask64,
    float* __restrict__ out_labels, float* __restrict__ out_bboxes,
    float* __restrict__ out_fg,
    float* __restrict__ pos_align, float* __restrict__ pos_over,
    int A, int n, int C)
{
    __shared__ float4 sg[64];
    __shared__ int    sl[64];
    const int b = blockIdx.y;
    const int a = blockIdx.x * 256 + threadIdx.x;
    if (threadIdx.x < n) {
        sg[threadIdx.x] = ((const float4*)gt_bboxes)[b * n + threadIdx.x];
        sl[threadIdx.x] = gt_labels[b * n + threadIdx.x];
    }
    __syncthreads();
    if (a >= A) return;

    const size_t midx = (size_t)b * A + a;
    u64 m = mask64[midx];
    int pc = __popcll(m);
    int jt = 0;
    if (pc > 1) {
        const float* col = overlaps + (size_t)b * n * A + a;
        float bv = col[0]; int bj = 0;
        for (int jj = 1; jj < n; ++jj) {
            float v = col[(size_t)jj * A];
            if (v > bv) { bv = v; bj = jj; }
        }
        jt = bj; mask64[midx] = 1ull << bj; pc = 1;
    } else if (pc == 1) {
        jt = __ffsll(m) - 1;
    }

    int lab = sl[jt];
    out_labels[midx] = (float)(lab < 0 ? 0 : lab);
    ((float4*)out_bboxes)[midx] = sg[jt];
    out_fg[midx] = pc ? 1.f : 0.f;

    if (pc) {
        int rowj = b * n + jt;
        float iou = overlaps[(size_t)rowj * A + a];
        float s = pd_scores[((size_t)b * A + a) * C + lab];
        float al = sqrtf(s) * powf(iou, 6.0f);
        atomicMax((int*)&pos_align[rowj], __float_as_int(al));
        atomicMax((int*)&pos_over[rowj],  __float_as_int(iou));
    }
}

// ---------------------------------------------------------------------------
// K4: one thread per (b,a): resolved mask popc<=1 ->
// norm = align * pos_over[row] / (pos_align[row] + eps)
// ---------------------------------------------------------------------------
__global__ __launch_bounds__(256) void k_norm(
    const float* __restrict__ pd_scores, const int* __restrict__ gt_labels,
    const float* __restrict__ overlaps, const u64* __restrict__ mask64,
    const float* __restrict__ pos_align, const float* __restrict__ pos_over,
    float* __restrict__ normv, int A, int n, int C, int total)
{
    int idx = blockIdx.x * 256 + threadIdx.x;
    if (idx >= total) return;
    int b = idx / A;
    int a = idx - b * A;
    u64 m = mask64[idx];
    float nm = 0.f;
    if (m) {
        int jj = __ffsll(m) - 1;
        int rowj = b * n + jj;
        float iou = overlaps[(size_t)rowj * A + a];
        float s = pd_scores[(size_t)idx * C + gt_labels[rowj]];
        float al = sqrtf(s) * powf(iou, 6.0f);
        nm = al * pos_over[rowj] / (pos_align[rowj] + EPSF);
    }
    normv[idx] = nm;
}

// ---------------------------------------------------------------------------
// K5: float4 per thread: score[b,a,c] = (fg && c==label) ? norm : 0
// ---------------------------------------------------------------------------
__global__ __launch_bounds__(256) void k_scores(
    const float* __restrict__ out_labels, const float* __restrict__ out_fg,
    const float* __restrict__ normv, float4* __restrict__ out_scores,
    int C4, int quads)
{
    int idx = blockIdx.x * 256 + threadIdx.x;
    if (idx >= quads) return;
    int ba = idx / C4;
    int q  = idx - ba * C4;
    float4 v = make_float4(0.f, 0.f, 0.f, 0.f);
    if (out_fg[ba] > 0.f) {
        int r = (int)out_labels[ba] - q * 4;
        float nv = normv[ba];
        v.x = (r == 0) ? nv : 0.f;
        v.y = (r == 1) ? nv : 0.f;
        v.z = (r == 2) ? nv : 0.f;
        v.w = (r == 3) ? nv : 0.f;
    }
    out_scores[idx] = v;
}

// ---------------------------------------------------------------------------
extern "C" void kernel_launch(void* const* d_in, const int* in_sizes, int n_in,
                              void* d_out, int out_size, void* d_ws, size_t ws_size,
                              hipStream_t stream)
{
    const float* pd_scores = (const float*)d_in[0];
    const float* pd_bboxes = (const float*)d_in[1];
    const float* anc       = (const float*)d_in[2];
    const int*   gt_labels = (const int*)d_in[3];
    const float* gt_bboxes = (const float*)d_in[4];

    const int C  = 80;                       // NUM_CLASSES
    const int A  = in_sizes[2] / 2;          // 8400
    const int bs = in_sizes[0] / (A * C);    // 16
    const int n  = in_sizes[3] / bs;         // 64
    const int R  = bs * n;                   // 1024
    const int BA = bs * A;                   // 134400

    // ws: [mask64 | pos_align | pos_over] (zeroed) | overlaps | normv | part
    size_t off = 0;
    u64*   mask64    = (u64*)((char*)d_ws + off);   off += (size_t)BA * 8;
    float* pos_align = (float*)((char*)d_ws + off); off += (size_t)R * 4;
    float* pos_over  = (float*)((char*)d_ws + off); off += (size_t)R * 4;
    size_t zero_bytes = off;
    float* overlaps  = (float*)((char*)d_ws + off); off += (size_t)R * A * 4;
    float* normv     = (float*)((char*)d_ws + off); off += (size_t)BA * 4;
    u64*   part      = (u64*)((char*)d_ws + off);   off += (size_t)R * CHUNKS * TOPK * 8;

    float* out_labels = (float*)d_out;
    float* out_bboxes = out_labels + (size_t)BA;
    float* out_scores = out_bboxes + (size_t)BA * 4;
    float* out_fg     = out_scores + (size_t)BA * C;

    int n16 = (int)(zero_bytes / 16);
    k_init<<<(n16 + 255) / 256, 256, 0, stream>>>((uint4*)d_ws, n16);

    // R*CHUNKS waves, 4 waves (256 threads) per block
    k_chunk<<<R * CHUNKS / 4, 256, 0, stream>>>(
        pd_scores, pd_bboxes, anc, gt_labels, gt_bboxes, overlaps, part, A, n, C);

    k_merge<<<(R + 63) / 64, 64, 0, stream>>>(
        anc, gt_bboxes, part, mask64, A, n, R);

    k_col<<<dim3((A + 255) / 256, bs), 256, 0, stream>>>(
        pd_scores, gt_labels, gt_bboxes, overlaps, mask64,
        out_labels, out_bboxes, out_fg, pos_align, pos_over, A, n, C);

    k_norm<<<(BA + 255) / 256, 256, 0, stream>>>(
        pd_scores, gt_labels, overlaps, mask64, pos_align, pos_over,
        normv, A, n, C, BA);

    int quads = BA * (C / 4);
    k_scores<<<(quads + 255) / 256, 256, 0, stream>>>(
        out_labels, out_fg, normv, (float4*)out_scores, C / 4, quads);
}

// Round 7
// 151.069 us; speedup vs baseline: 1.5958x; 1.1188x over previous
//
#include <hip/hip_runtime.h>

#define TOPK 10
#define EPSF 1e-9f
#define CHUNKS 8

typedef unsigned long long u64;
typedef unsigned int u32;

// Shared expression trees -> identical FP contraction at every call site ->
// bit-identical values across kernels (required: met==0 vs met>0 partition,
// and bitwise match vs XLA validated in R2-R4).
__device__ __forceinline__ float gt_area(const float4 g) {
    return fmaxf(g.z - g.x, 0.f) * fmaxf(g.w - g.y, 0.f);
}
__device__ __forceinline__ float iou_pair(const float4 g, const float4 p, float ga) {
    float ow = fmaxf(fminf(g.z, p.z) - fmaxf(g.x, p.x), 0.f) *
               fmaxf(fminf(g.w, p.w) - fmaxf(g.y, p.y), 0.f);
    float pa = fmaxf(p.z - p.x, 0.f) * fmaxf(p.w - p.y, 0.f);
    return ow / (ga + pa - ow + EPSF);
}
__device__ __forceinline__ float dmin_f(const float4 g, const float2 ap) {
    return fminf(fminf(ap.x - g.x, ap.y - g.y), fminf(g.z - ap.x, g.w - ap.y));
}
__device__ __forceinline__ u64 wave_max_u64(u64 v) {
    #pragma unroll
    for (int s = 1; s < 64; s <<= 1) {
        u64 o = __shfl_xor(v, s, 64);
        v = (o > v) ? o : v;
    }
    return v;
}

// ---------------------------------------------------------------------------
// K0: zero [mask64 | pos_align | pos_over] (ws poisoned before every call)
// ---------------------------------------------------------------------------
__global__ __launch_bounds__(256) void k_init(uint4* __restrict__ p, int n16) {
    int i = blockIdx.x * 256 + threadIdx.x;
    if (i < n16) p[i] = make_uint4(0, 0, 0, 0);
}

// ---------------------------------------------------------------------------
// K1: one wave per (row, chunk). Fast path: dmin test only (~25% of pairs are
// even worth a box load is false: ~0.4% in-gts). Insert POSITIVE metric keys
// only; key = (met_bits<<32)|(0x7fffffff-a)  == (value desc, index asc).
// Early-exit butterfly; part gets positives desc then zeros.
// ---------------------------------------------------------------------------
__global__ __launch_bounds__(256) void k_chunk(
    const float* __restrict__ pd_scores, const float* __restrict__ pd_bboxes,
    const float* __restrict__ anc, const int* __restrict__ gt_labels,
    const float* __restrict__ gt_bboxes, u64* __restrict__ part,
    int A, int n, int C)
{
    const int gw   = blockIdx.x * 4 + (threadIdx.x >> 6);
    const int lane = threadIdx.x & 63;
    const int row  = gw >> 3;                    // CHUNKS = 8
    const int ch   = gw & (CHUNKS - 1);
    const int b    = row / n;
    const int CS   = (A + CHUNKS - 1) / CHUNKS;  // 1050
    const int a0   = ch * CS;
    const int a1   = min(A, a0 + CS);

    const float4 g = *(const float4*)(gt_bboxes + (size_t)row * 4);
    const int    c = gt_labels[row];
    const float* ps = pd_scores + (size_t)b * A * C + c;
    const float4* pb = (const float4*)(pd_bboxes + (size_t)b * A * 4);
    const float2* an2 = (const float2*)anc;
    const float ga = gt_area(g);

    u64 tk[TOPK];
    #pragma unroll
    for (int k = 0; k < TOPK; ++k) tk[k] = 0;

    for (int a = a0 + lane; a < a1; a += 64) {
        float2 ap = an2[a];
        float dmin = dmin_f(g, ap);
        if (dmin > EPSF) {                       // ~0.4% of pairs
            float iou = iou_pair(g, pb[a], ga);
            float met = sqrtf(ps[(size_t)a * C]) * powf(iou, 6.0f);
            if (met > 0.f) {                     // positives are ~rare
                u64 key = ((u64)__float_as_uint(met) << 32) | (u32)(0x7fffffff - a);
                if (key > tk[TOPK-1]) {
                    tk[TOPK-1] = key;
                    #pragma unroll
                    for (int k = TOPK-1; k > 0; --k)
                        if (tk[k] > tk[k-1]) { u64 t = tk[k]; tk[k] = tk[k-1]; tk[k-1] = t; }
                }
            }
        }
    }

    u64 mine = 0;
    #pragma unroll
    for (int r = 0; r < TOPK; ++r) {
        u64 m = wave_max_u64(tk[0]);
        if (m == 0) break;                       // positives exhausted (uniform)
        if (lane == r) mine = m;
        if (tk[0] == m) {                        // unique owner pops
            #pragma unroll
            for (int k = 0; k < TOPK - 1; ++k) tk[k] = tk[k + 1];
            tk[TOPK-1] = 0;
        }
    }
    if (lane < TOPK)
        part[((size_t)row * CHUNKS + ch) * TOPK + lane] = mine;  // zeros pad
}

// ---------------------------------------------------------------------------
// K2: one wave per row. Merge positive keys (wave-max over the 80 part
// entries, pop, repeat); validity = top met > EPS; then zero-fill with the
// lowest-index met==0 anchors (ref tie semantics) up to 10 picks total.
// Commit = in_gts re-check + atomicOr bit j. Positives/zeros are disjoint.
// ---------------------------------------------------------------------------
__global__ __launch_bounds__(256) void k_merge(
    const float* __restrict__ pd_scores, const float* __restrict__ pd_bboxes,
    const float* __restrict__ anc, const int* __restrict__ gt_labels,
    const float* __restrict__ gt_bboxes,
    const u64* __restrict__ part, u64* __restrict__ mask64,
    int A, int n, int C)
{
    const int row  = blockIdx.x * 4 + (threadIdx.x >> 6);
    const int lane = threadIdx.x & 63;
    const int b    = row / n;
    const int j    = row - b * n;

    const u64* l = part + (size_t)row * (CHUNKS * TOPK);
    u64 e0 = l[lane];
    u64 e1 = (lane < CHUNKS * TOPK - 64) ? l[64 + lane] : 0;

    const float4 g = *(const float4*)(gt_bboxes + (size_t)row * 4);
    const int    c = gt_labels[row];
    const float* ps = pd_scores + (size_t)b * A * C + c;
    const float4* pb = (const float4*)(pd_bboxes + (size_t)b * A * 4);
    const float2* an2 = (const float2*)anc;
    const float ga = gt_area(g);
    u64* mrow = mask64 + (size_t)b * A;

    int npos = 0;
    bool invalid = false;
    u64 mine = 0;
    for (int r = 0; r < TOPK; ++r) {
        u64 me = (e0 > e1) ? e0 : e1;
        u64 m = wave_max_u64(me);
        if (r == 0) {
            float m0 = __uint_as_float((u32)(m >> 32));
            if (!(m0 > EPSF)) { invalid = true; break; }   // row invalid
        }
        if (m == 0) break;                       // positives exhausted
        if (lane == r) mine = m;
        if (e0 == m) e0 = 0; else if (e1 == m) e1 = 0;
        ++npos;
    }

    // commit positive picks (lanes 0..npos-1 hold them)
    if (lane < npos) {
        int a = 0x7fffffff - (int)(u32)(mine & 0xffffffffu);
        if (dmin_f(g, an2[a]) > EPSF)
            atomicOr(&mrow[a], 1ull << j);
    }

    // zero-fill: lowest-index anchors with met == 0 (exact recompute)
    if (!invalid) {
        int need = TOPK - npos;
        int base = 0;
        while (need > 0 && base < A) {
            int a = base + lane;
            float met = 1.f;                     // sentinel: excluded
            float dmin = -1.f;
            if (a < A) {
                float2 ap = an2[a];
                dmin = dmin_f(g, ap);
                met = 0.f;
                if (dmin > EPSF) {
                    float iou = iou_pair(g, pb[a], ga);
                    met = sqrtf(ps[(size_t)a * C]) * powf(iou, 6.0f);
                }
            }
            u64 zm = __ballot(met == 0.f);
            int cnt = __popcll(zm);
            int take = (need < cnt) ? need : cnt;
            int rank = __popcll(zm & ((1ull << lane) - 1ull));
            if (met == 0.f && rank < take && dmin > EPSF)
                atomicOr(&mrow[a], 1ull << j);
            need -= take;
            base += 64;
        }
    }
}

// ---------------------------------------------------------------------------
// K3: one thread per (b,a). Multi-assigned -> argmax_j IoU recomputed from
// registers+LDS (no memory walk). Writes labels/bboxes/fg; folds
// pos_align/pos_over via float-as-int atomicMax (all values >= 0).
// ---------------------------------------------------------------------------
__global__ __launch_bounds__(256) void k_col(
    const float* __restrict__ pd_scores, const float* __restrict__ pd_bboxes,
    const int* __restrict__ gt_labels, const float* __restrict__ gt_bboxes,
    u64* __restrict__ mask64,
    float* __restrict__ out_labels, float* __restrict__ out_bboxes,
    float* __restrict__ out_fg,
    float* __restrict__ pos_align, float* __restrict__ pos_over,
    int A, int n, int C)
{
    __shared__ float4 sg[64];
    __shared__ int    sl[64];
    const int b = blockIdx.y;
    const int a = blockIdx.x * 256 + threadIdx.x;
    if (threadIdx.x < n) {
        sg[threadIdx.x] = ((const float4*)gt_bboxes)[b * n + threadIdx.x];
        sl[threadIdx.x] = gt_labels[b * n + threadIdx.x];
    }
    __syncthreads();
    if (a >= A) return;

    const size_t midx = (size_t)b * A + a;
    u64 m = mask64[midx];
    int pc = __popcll(m);
    int jt = 0;
    float4 p;
    if (pc) p = ((const float4*)pd_bboxes)[midx];
    if (pc > 1) {
        // argmax over ALL j of iou(g_j, p), tie -> lowest j (== jnp.argmax)
        float bv = iou_pair(sg[0], p, gt_area(sg[0]));
        int bj = 0;
        for (int jj = 1; jj < n; ++jj) {
            float v = iou_pair(sg[jj], p, gt_area(sg[jj]));
            if (v > bv) { bv = v; bj = jj; }
        }
        jt = bj; mask64[midx] = 1ull << bj; pc = 1;
    } else if (pc == 1) {
        jt = __ffsll(m) - 1;
    }

    int lab = sl[jt];
    out_labels[midx] = (float)(lab < 0 ? 0 : lab);
    ((float4*)out_bboxes)[midx] = sg[jt];
    out_fg[midx] = pc ? 1.f : 0.f;

    if (pc) {
        int rowj = b * n + jt;
        float4 gj = sg[jt];
        float iou = iou_pair(gj, p, gt_area(gj));
        float s = pd_scores[midx * C + lab];
        float al = sqrtf(s) * powf(iou, 6.0f);
        atomicMax((int*)&pos_align[rowj], __float_as_int(al));
        atomicMax((int*)&pos_over[rowj],  __float_as_int(iou));
    }
}

// ---------------------------------------------------------------------------
// K4: one thread per (b,a): norm = al * pos_over[j] / (pos_align[j] + eps)
// for the (single) assigned j, else 0.
// ---------------------------------------------------------------------------
__global__ __launch_bounds__(256) void k_norm(
    const float* __restrict__ pd_scores, const float* __restrict__ pd_bboxes,
    const int* __restrict__ gt_labels, const float* __restrict__ gt_bboxes,
    const u64* __restrict__ mask64,
    const float* __restrict__ pos_align, const float* __restrict__ pos_over,
    float* __restrict__ normv, int A, int n, int C, int total)
{
    int idx = blockIdx.x * 256 + threadIdx.x;
    if (idx >= total) return;
    int b = idx / A;
    u64 m = mask64[idx];
    float nm = 0.f;
    if (m) {
        int jt = __ffsll(m) - 1;
        int rowj = b * n + jt;
        float4 gj = *(const float4*)(gt_bboxes + (size_t)rowj * 4);
        float4 p  = ((const float4*)pd_bboxes)[idx];
        float iou = iou_pair(gj, p, gt_area(gj));
        float s = pd_scores[(size_t)idx * C + gt_labels[rowj]];
        float al = sqrtf(s) * powf(iou, 6.0f);
        nm = al * pos_over[rowj] / (pos_align[rowj] + EPSF);
    }
    normv[idx] = nm;
}

// ---------------------------------------------------------------------------
// K5: float4 per thread: score[b,a,c] = (fg && c==label) ? norm : 0
// ---------------------------------------------------------------------------
__global__ __launch_bounds__(256) void k_scores(
    const float* __restrict__ out_labels, const float* __restrict__ out_fg,
    const float* __restrict__ normv, float4* __restrict__ out_scores,
    int C4, int quads)
{
    int idx = blockIdx.x * 256 + threadIdx.x;
    if (idx >= quads) return;
    int ba = idx / C4;
    int q  = idx - ba * C4;
    float4 v = make_float4(0.f, 0.f, 0.f, 0.f);
    if (out_fg[ba] > 0.f) {
        int r = (int)out_labels[ba] - q * 4;
        float nv = normv[ba];
        v.x = (r == 0) ? nv : 0.f;
        v.y = (r == 1) ? nv : 0.f;
        v.z = (r == 2) ? nv : 0.f;
        v.w = (r == 3) ? nv : 0.f;
    }
    out_scores[idx] = v;
}

// ---------------------------------------------------------------------------
extern "C" void kernel_launch(void* const* d_in, const int* in_sizes, int n_in,
                              void* d_out, int out_size, void* d_ws, size_t ws_size,
                              hipStream_t stream)
{
    const float* pd_scores = (const float*)d_in[0];
    const float* pd_bboxes = (const float*)d_in[1];
    const float* anc       = (const float*)d_in[2];
    const int*   gt_labels = (const int*)d_in[3];
    const float* gt_bboxes = (const float*)d_in[4];

    const int C  = 80;                       // NUM_CLASSES
    const int A  = in_sizes[2] / 2;          // 8400
    const int bs = in_sizes[0] / (A * C);    // 16
    const int n  = in_sizes[3] / bs;         // 64
    const int R  = bs * n;                   // 1024
    const int BA = bs * A;                   // 134400

    // ws: [mask64 | pos_align | pos_over] (zeroed) | normv | part   (~2.3 MB)
    size_t off = 0;
    u64*   mask64    = (u64*)((char*)d_ws + off);   off += (size_t)BA * 8;
    float* pos_align = (float*)((char*)d_ws + off); off += (size_t)R * 4;
    float* pos_over  = (float*)((char*)d_ws + off); off += (size_t)R * 4;
    size_t zero_bytes = off;
    float* normv = (float*)((char*)d_ws + off);     off += (size_t)BA * 4;
    u64*   part  = (u64*)((char*)d_ws + off);       off += (size_t)R * CHUNKS * TOPK * 8;

    float* out_labels = (float*)d_out;
    float* out_bboxes = out_labels + (size_t)BA;
    float* out_scores = out_bboxes + (size_t)BA * 4;
    float* out_fg     = out_scores + (size_t)BA * C;

    int n16 = (int)(zero_bytes / 16);
    k_init<<<(n16 + 255) / 256, 256, 0, stream>>>((uint4*)d_ws, n16);

    k_chunk<<<R * CHUNKS / 4, 256, 0, stream>>>(
        pd_scores, pd_bboxes, anc, gt_labels, gt_bboxes, part, A, n, C);

    k_merge<<<R / 4, 256, 0, stream>>>(
        pd_scores, pd_bboxes, anc, gt_labels, gt_bboxes, part, mask64, A, n, C);

    k_col<<<dim3((A + 255) / 256, bs), 256, 0, stream>>>(
        pd_scores, pd_bboxes, gt_labels, gt_bboxes, mask64,
        out_labels, out_bboxes, out_fg, pos_align, pos_over, A, n, C);

    k_norm<<<(BA + 255) / 256, 256, 0, stream>>>(
        pd_scores, pd_bboxes, gt_labels, gt_bboxes, mask64,
        pos_align, pos_over, normv, A, n, C, BA);

    int quads = BA * (C / 4);
    k_scores<<<(quads + 255) / 256, 256, 0, stream>>>(
        out_labels, out_fg, normv, (float4*)out_scores, C / 4, quads);
}

// Round 9
// 147.356 us; speedup vs baseline: 1.6361x; 1.0252x over previous
//
#include <hip/hip_runtime.h>

#define TOPK 10
#define EPSF 1e-9f
#define CAP  1024   // per-row candidate capacity (max physically ~110)

typedef unsigned long long u64;
typedef unsigned int u32;

// Shared expression trees -> identical FP contraction at every call site ->
// bit-identical values across kernels (validated absmax==0.0 in R2-R7).
__device__ __forceinline__ float gt_area(const float4 g) {
    return fmaxf(g.z - g.x, 0.f) * fmaxf(g.w - g.y, 0.f);
}
__device__ __forceinline__ float iou_pair(const float4 g, const float4 p, float ga) {
    float ow = fmaxf(fminf(g.z, p.z) - fmaxf(g.x, p.x), 0.f) *
               fmaxf(fminf(g.w, p.w) - fmaxf(g.y, p.y), 0.f);
    float pa = fmaxf(p.z - p.x, 0.f) * fmaxf(p.w - p.y, 0.f);
    return ow / (ga + pa - ow + EPSF);
}
__device__ __forceinline__ float dmin_f(const float4 g, const float2 ap) {
    return fminf(fminf(ap.x - g.x, ap.y - g.y), fminf(g.z - ap.x, g.w - ap.y));
}
__device__ __forceinline__ u64 wave_max_u64(u64 v) {
    #pragma unroll
    for (int s = 1; s < 64; s <<= 1) {
        u64 o = __shfl_xor(v, s, 64);
        v = (o > v) ? o : v;
    }
    return v;
}

// ---------------------------------------------------------------------------
// K0: zero [mask64 | pos_align | pos_over | cand_cnt]
// ---------------------------------------------------------------------------
__global__ __launch_bounds__(256) void k_init(uint4* __restrict__ p, int n16) {
    int i = blockIdx.x * 256 + threadIdx.x;
    if (i < n16) p[i] = make_uint4(0, 0, 0, 0);
}

// ---------------------------------------------------------------------------
// K1: thread per (b,a). gt boxes/areas/labels in LDS; loop 64 gts:
// 7-op dmin test; on pass (~0.4%), met = sqrt(score)*iou^6; met>0 ->
// push key (met_bits<<32)|(0x7fffffff-a) into per-row candidate list.
// Key order == (value desc, index asc) == jax.lax.top_k ordering.
// ---------------------------------------------------------------------------
__global__ __launch_bounds__(256) void k_cand(
    const float* __restrict__ pd_scores, const float* __restrict__ pd_bboxes,
    const float* __restrict__ anc, const int* __restrict__ gt_labels,
    const float* __restrict__ gt_bboxes,
    u64* __restrict__ cand, int* __restrict__ cnt,
    int A, int n, int C)
{
    __shared__ float4 sg[64];
    __shared__ float  sga[64];
    __shared__ int    sl[64];
    const int b = blockIdx.y;
    const int a = blockIdx.x * 256 + threadIdx.x;
    if (threadIdx.x < n) {
        float4 g4 = ((const float4*)gt_bboxes)[b * n + threadIdx.x];
        sg[threadIdx.x]  = g4;
        sga[threadIdx.x] = gt_area(g4);
        sl[threadIdx.x]  = gt_labels[b * n + threadIdx.x];
    }
    __syncthreads();
    if (a >= A) return;

    const float2 ap = ((const float2*)anc)[a];
    const float4 p  = ((const float4*)pd_bboxes)[(size_t)b * A + a];
    const float* psa = pd_scores + ((size_t)b * A + a) * C;

    for (int jj = 0; jj < n; ++jj) {
        float4 g = sg[jj];
        float dmin = dmin_f(g, ap);
        if (dmin > EPSF) {                       // ~0.4% of (a,j) pairs
            float iou = iou_pair(g, p, sga[jj]);
            float met = sqrtf(psa[sl[jj]]) * powf(iou, 6.0f);
            if (met > 0.f) {
                int row = b * n + jj;
                u64 key = ((u64)__float_as_uint(met) << 32) | (u32)(0x7fffffff - a);
                int pos = atomicAdd(&cnt[row], 1);
                if (pos < CAP) cand[(size_t)row * CAP + pos] = key;
            }
        }
    }
}

// ---------------------------------------------------------------------------
// K2: one wave per row. Top-10 of the candidate list (per-lane top-10 +
// butterfly pops); validity = max met > EPS; zero-fill with lowest-index
// met==0 anchors (windowed scan; exact ref tie semantics: zeros include
// out-gts anchors, commit only in-gts). Commit via atomicOr bit j.
// ---------------------------------------------------------------------------
__global__ __launch_bounds__(256) void k_top(
    const float* __restrict__ pd_scores, const float* __restrict__ pd_bboxes,
    const float* __restrict__ anc, const int* __restrict__ gt_labels,
    const float* __restrict__ gt_bboxes,
    const u64* __restrict__ cand, const int* __restrict__ cnt,
    u64* __restrict__ mask64, int A, int n, int C)
{
    const int row  = blockIdx.x * 4 + (threadIdx.x >> 6);
    const int lane = threadIdx.x & 63;
    const int b    = row / n;
    const int j    = row - b * n;
    const int m_cnt = min(cnt[row], CAP);
    const u64* cl = cand + (size_t)row * CAP;

    u64 tk[TOPK];
    #pragma unroll
    for (int k = 0; k < TOPK; ++k) tk[k] = 0;
    for (int e = lane; e < m_cnt; e += 64) {     // usually 0 or 1 key per lane
        u64 key = cl[e];
        if (key > tk[TOPK-1]) {
            tk[TOPK-1] = key;
            #pragma unroll
            for (int k = TOPK-1; k > 0; --k)
                if (tk[k] > tk[k-1]) { u64 t = tk[k]; tk[k] = tk[k-1]; tk[k-1] = t; }
        }
    }

    int npos = 0;
    bool invalid = false;
    u64 mine = 0;
    #pragma unroll
    for (int r = 0; r < TOPK; ++r) {
        u64 m = wave_max_u64(tk[0]);
        if (r == 0) {
            float m0 = __uint_as_float((u32)(m >> 32));
            if (!(m0 > EPSF)) { invalid = true; break; }   // row invalid
        }
        if (m == 0) break;                       // positives exhausted
        if (lane == r) mine = m;
        if (tk[0] == m) {                        // unique owner pops
            #pragma unroll
            for (int k = 0; k < TOPK - 1; ++k) tk[k] = tk[k + 1];
            tk[TOPK-1] = 0;
        }
        ++npos;
    }

    u64* mrow = mask64 + (size_t)b * A;
    // commit positives (candidates are in-gts by construction)
    if (lane < npos) {
        int a = 0x7fffffff - (int)(u32)(mine & 0xffffffffu);
        atomicOr(&mrow[a], 1ull << j);
    }
    // zero-fill: lowest-index met==0 anchors (windowed; commit only in-gts)
    if (!invalid && npos < TOPK) {
        const float4 g = *(const float4*)(gt_bboxes + (size_t)row * 4);
        const float ga = gt_area(g);
        const int   c  = gt_labels[row];
        const float* ps = pd_scores + (size_t)b * A * C + c;
        const float4* pb = (const float4*)(pd_bboxes + (size_t)b * A * 4);
        int need = TOPK - npos;
        int base = 0;
        while (need > 0 && base < A) {
            const int a = base + lane;
            float met = 1.f;                     // sentinel: excluded
            float dmin = -1.f;
            if (a < A) {
                float2 ap = ((const float2*)anc)[a];
                dmin = dmin_f(g, ap);
                met = 0.f;
                if (dmin > EPSF) {
                    float iou = iou_pair(g, pb[a], ga);
                    met = sqrtf(ps[(size_t)a * C]) * powf(iou, 6.0f);
                }
            }
            u64 zm = __ballot(met == 0.f);
            int cntz = __popcll(zm);
            int take = (need < cntz) ? need : cntz;
            int rank = __popcll(zm & ((1ull << lane) - 1ull));
            if (met == 0.f && rank < take && dmin > EPSF)
                atomicOr(&mrow[a], 1ull << j);
            need -= take;
            base += 64;
        }
    }
}

// ---------------------------------------------------------------------------
// K3: thread per (b,a). Multi-assigned -> argmax_j IoU from LDS (tie ->
// lowest j). Writes labels/bboxes/fg; stores al to ws; folds
// pos_align/pos_over via float-as-int atomicMax (all values >= 0).
// ---------------------------------------------------------------------------
__global__ __launch_bounds__(256) void k_col(
    const float* __restrict__ pd_scores, const float* __restrict__ pd_bboxes,
    const int* __restrict__ gt_labels, const float* __restrict__ gt_bboxes,
    u64* __restrict__ mask64,
    float* __restrict__ out_labels, float* __restrict__ out_bboxes,
    float* __restrict__ out_fg, float* __restrict__ alv,
    float* __restrict__ pos_align, float* __restrict__ pos_over,
    int A, int n, int C)
{
    __shared__ float4 sg[64];
    __shared__ int    sl[64];
    const int b = blockIdx.y;
    const int a = blockIdx.x * 256 + threadIdx.x;
    if (threadIdx.x < n) {
        sg[threadIdx.x] = ((const float4*)gt_bboxes)[b * n + threadIdx.x];
        sl[threadIdx.x] = gt_labels[b * n + threadIdx.x];
    }
    __syncthreads();
    if (a >= A) return;

    const size_t midx = (size_t)b * A + a;
    u64 m = mask64[midx];
    int pc = __popcll(m);
    int jt = 0;
    float4 p;
    if (pc) p = ((const float4*)pd_bboxes)[midx];
    if (pc > 1) {
        float bv = iou_pair(sg[0], p, gt_area(sg[0]));
        int bj = 0;
        for (int jj = 1; jj < n; ++jj) {
            float v = iou_pair(sg[jj], p, gt_area(sg[jj]));
            if (v > bv) { bv = v; bj = jj; }
        }
        jt = bj; mask64[midx] = 1ull << bj; pc = 1;
    } else if (pc == 1) {
        jt = __ffsll(m) - 1;
    }

    int lab = sl[jt];
    out_labels[midx] = (float)(lab < 0 ? 0 : lab);
    ((float4*)out_bboxes)[midx] = sg[jt];
    out_fg[midx] = pc ? 1.f : 0.f;

    if (pc) {
        int rowj = b * n + jt;
        float4 gj = sg[jt];
        float iou = iou_pair(gj, p, gt_area(gj));
        float s = pd_scores[midx * C + lab];
        float al = sqrtf(s) * powf(iou, 6.0f);
        alv[midx] = al;
        atomicMax((int*)&pos_align[rowj], __float_as_int(al));
        atomicMax((int*)&pos_over[rowj],  __float_as_int(iou));
    }
}

// ---------------------------------------------------------------------------
// K4: thread per (b,a): norm = al * pos_over[j] / (pos_align[j] + eps)
// ---------------------------------------------------------------------------
__global__ __launch_bounds__(256) void k_norm(
    const u64* __restrict__ mask64, const float* __restrict__ alv,
    const float* __restrict__ pos_align, const float* __restrict__ pos_over,
    float* __restrict__ normv, int A, int n, int total)
{
    int idx = blockIdx.x * 256 + threadIdx.x;
    if (idx >= total) return;
    int b = idx / A;
    u64 m = mask64[idx];
    float nm = 0.f;
    if (m) {
        int rowj = b * n + (__ffsll(m) - 1);
        nm = alv[idx] * pos_over[rowj] / (pos_align[rowj] + EPSF);
    }
    normv[idx] = nm;
}

// ---------------------------------------------------------------------------
// K5: float4 per thread: score[b,a,c] = (fg && c==label) ? norm : 0
// ---------------------------------------------------------------------------
__global__ __launch_bounds__(256) void k_scores(
    const float* __restrict__ out_labels, const float* __restrict__ out_fg,
    const float* __restrict__ normv, float4* __restrict__ out_scores,
    int C4, int quads)
{
    int idx = blockIdx.x * 256 + threadIdx.x;
    if (idx >= quads) return;
    int ba = idx / C4;
    int q  = idx - ba * C4;
    float4 v = make_float4(0.f, 0.f, 0.f, 0.f);
    if (out_fg[ba] > 0.f) {
        int r = (int)out_labels[ba] - q * 4;
        float nv = normv[ba];
        v.x = (r == 0) ? nv : 0.f;
        v.y = (r == 1) ? nv : 0.f;
        v.z = (r == 2) ? nv : 0.f;
        v.w = (r == 3) ? nv : 0.f;
    }
    out_scores[idx] = v;
}

// ---------------------------------------------------------------------------
extern "C" void kernel_launch(void* const* d_in, const int* in_sizes, int n_in,
                              void* d_out, int out_size, void* d_ws, size_t ws_size,
                              hipStream_t stream)
{
    const float* pd_scores = (const float*)d_in[0];
    const float* pd_bboxes = (const float*)d_in[1];
    const float* anc       = (const float*)d_in[2];
    const int*   gt_labels = (const int*)d_in[3];
    const float* gt_bboxes = (const float*)d_in[4];

    const int C  = 80;                       // NUM_CLASSES
    const int A  = in_sizes[2] / 2;          // 8400
    const int bs = in_sizes[0] / (A * C);    // 16
    const int n  = in_sizes[3] / bs;         // 64
    const int R  = bs * n;                   // 1024
    const int BA = bs * A;                   // 134400

    // ws: [mask64 | pos_align | pos_over | cnt] (zeroed) | alv | normv | cand
    size_t off = 0;
    u64*   mask64    = (u64*)((char*)d_ws + off);   off += (size_t)BA * 8;
    float* pos_align = (float*)((char*)d_ws + off); off += (size_t)R * 4;
    float* pos_over  = (float*)((char*)d_ws + off); off += (size_t)R * 4;
    int*   cand_cnt  = (int*)((char*)d_ws + off);   off += (size_t)R * 4;
    size_t zero_bytes = off;
    float* alv   = (float*)((char*)d_ws + off);     off += (size_t)BA * 4;
    float* normv = (float*)((char*)d_ws + off);     off += (size_t)BA * 4;
    u64*   cand  = (u64*)((char*)d_ws + off);       off += (size_t)R * CAP * 8;

    float* out_labels = (float*)d_out;
    float* out_bboxes = out_labels + (size_t)BA;
    float* out_scores = out_bboxes + (size_t)BA * 4;
    float* out_fg     = out_scores + (size_t)BA * C;

    int n16 = (int)(zero_bytes / 16);
    k_init<<<(n16 + 255) / 256, 256, 0, stream>>>((uint4*)d_ws, n16);

    k_cand<<<dim3((A + 255) / 256, bs), 256, 0, stream>>>(
        pd_scores, pd_bboxes, anc, gt_labels, gt_bboxes, cand, cand_cnt, A, n, C);

    k_top<<<R / 4, 256, 0, stream>>>(
        pd_scores, pd_bboxes, anc, gt_labels, gt_bboxes, cand, cand_cnt,
        mask64, A, n, C);

    k_col<<<dim3((A + 255) / 256, bs), 256, 0, stream>>>(
        pd_scores, pd_bboxes, gt_labels, gt_bboxes, mask64,
        out_labels, out_bboxes, out_fg, alv, pos_align, pos_over, A, n, C);

    k_norm<<<(BA + 255) / 256, 256, 0, stream>>>(
        mask64, alv, pos_align, pos_over, normv, A, n, BA);

    int quads = BA * (C / 4);
    k_scores<<<(quads + 255) / 256, 256, 0, stream>>>(
        out_labels, out_fg, normv, (float4*)out_scores, C / 4, quads);
}